// Round 14
// baseline (172.507 us; speedup 1.0000x reference)
//
#include <hip/hip_runtime.h>
#include <hip/hip_bf16.h>
#include <hip/hip_fp8.h>

#define N_ROWS 8192
#define NZ 16384           // rows of Z = [An; Bn]
#define DIM 256
#define BT 128             // block tile (square)
#define NTILE 128          // NZ / BT
#define NTRI (NTILE * (NTILE + 1) / 2)   // 8256 upper-tri tiles

typedef float f32x4 __attribute__((ext_vector_type(4)));
typedef long lx2 __attribute__((ext_vector_type(2)));   // 16B = 2 fp8 MFMA operands

// ---------------------------------------------------------------------------
// Kernel 1: one WAVE per row. L2-normalize, scale by ALPHA = sqrt(2*log2(e))
// (folds the exp2 scale INTO the fp8 values: MFMA dot == exp2 argument),
// quantize to OCP fp8 e4m3, write Z8 K-INTERLEAVED ([g0 g4 g1 g5 g2 g6 g3 g7]
// per 64B chunk) so one 16B granule = operand pair (g, g+4) for two MFMA
// K-steps. pos[i] = quantized dot (= 2*log2(e)*sim); loss uses ln2*pos.
// Also zeroes S (fallback accumulator) and out[0].
// ---------------------------------------------------------------------------
__global__ __launch_bounds__(256) void normalize_kernel(
    const float* __restrict__ z1, const float* __restrict__ z2,
    unsigned char* __restrict__ Z8, float* __restrict__ pos,
    float* __restrict__ S, float* __restrict__ out)
{
    const int tid = threadIdx.x;
    if (blockIdx.x < 64) S[blockIdx.x * 256 + tid] = 0.0f;   // 16384 floats
    if (blockIdx.x == 0 && tid == 0) out[0] = 0.0f;

    const int wave = tid >> 6;
    const int lane = tid & 63;
    const int row = blockIdx.x * 4 + wave;      // 0..8191

    const float4 a = ((const float4*)(z1 + (size_t)row * DIM))[lane];
    const float4 b = ((const float4*)(z2 + (size_t)row * DIM))[lane];

    auto wsum = [&](float v) -> float {
        #pragma unroll
        for (int m = 1; m < 64; m <<= 1) v += __shfl_xor(v, m, 64);
        return v;
    };

    const float na2 = wsum(a.x*a.x + a.y*a.y + a.z*a.z + a.w*a.w);
    const float nb2 = wsum(b.x*b.x + b.y*b.y + b.z*b.z + b.w*b.w);
    const float ALPHA = 1.6986436f;        // sqrt(2*log2(e))
    const float sa = ALPHA / sqrtf(na2);   // norms ~16; eps never binds
    const float sb = ALPHA / sqrtf(nb2);

    const float av[4] = {a.x*sa, a.y*sa, a.z*sa, a.w*sa};
    const float bv[4] = {b.x*sb, b.y*sb, b.z*sb, b.w*sb};
    unsigned char pa[4], pb[4];
    float qd = 0.0f;
    #pragma unroll
    for (int k = 0; k < 4; ++k) {
        __hip_fp8_e4m3 qa(av[k]);
        __hip_fp8_e4m3 qb(bv[k]);
        pa[k] = qa.__x; pb[k] = qb.__x;
        qd += float(qa) * float(qb);
    }
    // interleaved write: lane owns half (lane&1) of local K-group (lane>>1)&7
    const int g  = (lane >> 1) & 7;
    const int pp = ((g & 3) << 1) | (g >> 2);          // interleaved 8B slot
    const int off = (lane >> 4) * 64 + pp * 8 + (lane & 1) * 4;
    *(uchar4*)(Z8 + (size_t)row * DIM + off) = *(uchar4*)pa;
    *(uchar4*)(Z8 + (size_t)(N_ROWS + row) * DIM + off) = *(uchar4*)pb;

    qd = wsum(qd);
    if (lane == 0) pos[row] = qd;      // = 2*log2(e) * sim_quantized
}

// ---------------------------------------------------------------------------
// Kernel 2: symmetric fp8 gram, upper triangle, dense triangular grid.
// R13 core (measured: conflicts 0, VGPR 64, no spill): BK=128, 2 K-steps,
// width-16 staging, tile-invariant b128 frag reads, 16B-granule XOR swizzle.
// Epilogue: exp2(dot) DIRECT (scale folded into quant), diag mask, 512
// coalesced part floats per block. NO atomics in the hot path.
// ---------------------------------------------------------------------------
template <bool TWO_STAGE>
__global__ __launch_bounds__(256, 4) void gram_kernel(
    const unsigned char* __restrict__ Z,
    float* __restrict__ part, float* __restrict__ S)
{
    // XCD band remap (8256 = 8 * 1032), then triangular decode.
    const int bid = (blockIdx.x & 7) * (NTRI / 8) + (blockIdx.x >> 3);
    int ti = (int)((257.0f - sqrtf(66049.0f - 8.0f * (float)bid)) * 0.5f);
    ti = ti < 0 ? 0 : (ti > 127 ? 127 : ti);
    while (ti * (257 - ti) / 2 > bid) --ti;
    while ((ti + 1) * (256 - ti) / 2 <= bid) ++ti;
    const int tj = ti + (bid - ti * (257 - ti) / 2);
    const bool diag = (ti == tj);

    __shared__ unsigned char Ls[32768];   // A: [0,16K), B: [16K,32K)

    const int tid  = threadIdx.x;
    const int wave = tid >> 6;
    const int lane = tid & 63;
    const int wr = wave >> 1, wc = wave & 1;
    const int lm = lane & 15, lq = lane >> 4;

    // ---- staging lane geometry (width-16: 1KB instr = 8 rows x 8 granules)
    const int r8 = lane >> 3;                   // row within 8-row group
    const int pg = lane & 7;                    // LDS granule slot
    const int G0 = pg ^ (r8 >> 1);              // global granule, even instrs
    const int dlt = 64 - ((G0 & 4) << 5);       // odd instrs: granule G0^4
    const unsigned char* pAE =
        Z + (size_t)(ti * BT + wave * 32 + r8) * DIM + (G0 << 4);
    const unsigned char* pBE =
        Z + (size_t)(tj * BT + wave * 32 + r8) * DIM + (G0 << 4);
    const unsigned char* pAO = pAE + dlt;
    const unsigned char* pBO = pBE + dlt;

    // ---- frag-read bases (invariant across the whole tile)
    const int s0 = (lq ^ (lm >> 1)) << 4;       // slot of granule lq
    const int s1 = s0 ^ 64;                     // slot of granule lq^4
    const unsigned char* LA0 = Ls + wr * 8192 + lm * 128 + s0;
    const unsigned char* LA1 = Ls + wr * 8192 + lm * 128 + s1;
    const unsigned char* LB0 = Ls + 16384 + wc * 8192 + lm * 128 + s0;
    const unsigned char* LB1 = Ls + 16384 + wc * 8192 + lm * 128 + s1;

    f32x4 acc[4][4] = {};

    #pragma unroll
    for (int kh = 0; kh < 2; ++kh) {
        if (kh) __syncthreads();        // protect LDS reads of prev k-half
        #pragma unroll
        for (int c = 0; c < 4; ++c) {   // 4 A + 4 B instrs per wave
            const int ld = (wave * 4 + c) * 1024;       // wave-uniform dest
            const unsigned char* ga = ((c & 1) ? pAO : pAE) + c * 2048 + kh * 128;
            const unsigned char* gb = ((c & 1) ? pBO : pBE) + c * 2048 + kh * 128;
            __builtin_amdgcn_global_load_lds(
                (const __attribute__((address_space(1))) void*)ga,
                (__attribute__((address_space(3))) void*)(Ls + ld), 16, 0, 0);
            __builtin_amdgcn_global_load_lds(
                (const __attribute__((address_space(1))) void*)gb,
                (__attribute__((address_space(3))) void*)(Ls + 16384 + ld), 16, 0, 0);
        }
        __syncthreads();

        lx2 aP[4], bP[4];
        #pragma unroll
        for (int f = 0; f < 4; ++f) {
            aP[f] = *(const lx2*)(LA0 + f * 2048);
            bP[f] = *(const lx2*)(LB0 + f * 2048);
        }
        #pragma unroll
        for (int fr = 0; fr < 4; ++fr)
            #pragma unroll
            for (int fc = 0; fc < 4; ++fc) {
                acc[fr][fc] = __builtin_amdgcn_mfma_f32_16x16x32_fp8_fp8(
                    aP[fr].x, bP[fc].x, acc[fr][fc], 0, 0, 0);
                acc[fr][fc] = __builtin_amdgcn_mfma_f32_16x16x32_fp8_fp8(
                    aP[fr].y, bP[fc].y, acc[fr][fc], 0, 0, 0);
            }
        #pragma unroll
        for (int f = 0; f < 4; ++f) {
            aP[f] = *(const lx2*)(LA1 + f * 2048);
            bP[f] = *(const lx2*)(LB1 + f * 2048);
        }
        #pragma unroll
        for (int fr = 0; fr < 4; ++fr)
            #pragma unroll
            for (int fc = 0; fc < 4; ++fc) {
                acc[fr][fc] = __builtin_amdgcn_mfma_f32_16x16x32_fp8_fp8(
                    aP[fr].x, bP[fc].x, acc[fr][fc], 0, 0, 0);
                acc[fr][fc] = __builtin_amdgcn_mfma_f32_16x16x32_fp8_fp8(
                    aP[fr].y, bP[fc].y, acc[fr][fc], 0, 0, 0);
            }
    }
    // epilogue is LDS-free: no trailing barrier

    // dot already == exp2 argument (scale folded into quantization)
    #pragma unroll
    for (int fr = 0; fr < 4; ++fr)
        #pragma unroll
        for (int fc = 0; fc < 4; ++fc)
            #pragma unroll
            for (int r = 0; r < 4; ++r)
                acc[fr][fc][r] = exp2f(acc[fr][fc][r]);

    if (diag) {   // zero at-or-below-diagonal (each pair counted once)
        #pragma unroll
        for (int fr = 0; fr < 4; ++fr) {
            const int gi = wr * 64 + fr * 16 + lq * 4;
            #pragma unroll
            for (int fc = 0; fc < 4; ++fc) {
                const int gj = wc * 64 + fc * 16 + lm;
                #pragma unroll
                for (int r = 0; r < 4; ++r)
                    if (gj <= gi + r) acc[fr][fc][r] = 0.0f;
            }
        }
    }

    float* dst = TWO_STAGE ? (part + (size_t)bid * 512) : nullptr;

    // row partials over this wave's 64 cols (C/D: col=lane&15, row=lq*4+reg)
    #pragma unroll
    for (int fr = 0; fr < 4; ++fr)
        #pragma unroll
        for (int r = 0; r < 4; ++r) {
            float s = acc[fr][0][r] + acc[fr][1][r] + acc[fr][2][r] + acc[fr][3][r];
            s += __shfl_xor(s, 1, 64);
            s += __shfl_xor(s, 2, 64);
            s += __shfl_xor(s, 4, 64);
            s += __shfl_xor(s, 8, 64);
            if (lm == 0) {
                const int rr = wr * 64 + fr * 16 + lq * 4 + r;
                if (TWO_STAGE) dst[wc * 128 + rr] = s;
                else atomicAdd(&S[ti * BT + rr], s);
            }
        }
    // col partials over this wave's 64 rows (symmetry: colsum feeds S too)
    #pragma unroll
    for (int fc = 0; fc < 4; ++fc) {
        float s = 0.0f;
        #pragma unroll
        for (int fr = 0; fr < 4; ++fr)
            #pragma unroll
            for (int r = 0; r < 4; ++r) s += acc[fr][fc][r];
        s += __shfl_xor(s, 16, 64);
        s += __shfl_xor(s, 32, 64);
        if (lq == 0) {
            const int cc = wc * 64 + fc * 16 + lm;
            if (TWO_STAGE) dst[256 + wr * 128 + cc] = s;
            else atomicAdd(&S[tj * BT + cc], s);
        }
    }
}

// ---------------------------------------------------------------------------
// Kernel 3: FUSED reduce + loss. grid 64, block 1024 = [2 pair][4 slice][128].
// Block b gathers all 258 strips for tile pair (b, b+64): row-side blocks
// (t, tj>=t) slots {0,128}+rr; col-side blocks (ti<=t, t) slots 256+{0,128}+rr.
// All wave-loads are 256B coalesced. LDS-combine 4 slices, then loss rows
// i = b*128+rr (den1 from tile b, den2 from tile b+64), one atomic per block.
// ---------------------------------------------------------------------------
__global__ __launch_bounds__(1024) void reduce_loss_kernel(
    const float* __restrict__ part, const float* __restrict__ pos,
    float* __restrict__ out)
{
    const int tid = threadIdx.x;
    const int rr = tid & 127;
    const int sl = (tid >> 7) & 3;
    const int p  = tid >> 9;                    // 0: den1 (tile b), 1: den2 (b+64)
    const int t  = blockIdx.x + p * 64;         // Z tile index
    const int baseRow = t * (257 - t) / 2;
    const int cntRow = 2 * (128 - t);

    float s = 0.0f;
    for (int m = sl; m < 258; m += 4) {
        size_t addr;
        if (m < cntRow) {
            const int bb = baseRow + (m >> 1);
            addr = (size_t)bb * 512 + (m & 1) * 128 + rr;
        } else {
            const int m2 = m - cntRow;
            const int tiq = m2 >> 1;
            const int bb = tiq * (257 - tiq) / 2 + (t - tiq);
            addr = (size_t)bb * 512 + 256 + (m2 & 1) * 128 + rr;
        }
        s += part[addr];
    }

    __shared__ float L[2][4][128];
    __shared__ float red[2];
    L[p][sl][rr] = s;
    __syncthreads();

    if (tid < 128) {
        const float den1 = L[0][0][rr] + L[0][1][rr] + L[0][2][rr] + L[0][3][rr];
        const float den2 = L[1][0][rr] + L[1][1][rr] + L[1][2][rr] + L[1][3][rr];
        const int i = blockIdx.x * 128 + rr;
        // pos = 2*log2(e)*sim  ->  2*sim = ln2 * pos
        float v = 0.5f * (logf(den1) + logf(den2)) - 0.69314718056f * pos[i];
        #pragma unroll
        for (int mm = 1; mm < 64; mm <<= 1) v += __shfl_xor(v, mm, 64);
        if ((tid & 63) == 0) red[tid >> 6] = v;
    }
    __syncthreads();
    if (tid == 0)
        atomicAdd(out, (red[0] + red[1]) * (1.0f / N_ROWS));
}

// Fallback loss (atomic path, only if ws too small — not expected).
__global__ __launch_bounds__(256) void loss_kernel(
    const float* __restrict__ S, const float* __restrict__ pos,
    float* __restrict__ out)
{
    const int i = blockIdx.x * 256 + threadIdx.x;
    float v = 0.5f * (logf(S[i]) + logf(S[N_ROWS + i]))
              - 0.69314718056f * pos[i];

    __shared__ float red[4];
    #pragma unroll
    for (int m = 1; m < 64; m <<= 1) v += __shfl_xor(v, m, 64);
    if ((threadIdx.x & 63) == 0) red[threadIdx.x >> 6] = v;
    __syncthreads();
    if (threadIdx.x == 0)
        atomicAdd(out, (red[0] + red[1] + red[2] + red[3]) * (1.0f / N_ROWS));
}

// ---------------------------------------------------------------------------
extern "C" void kernel_launch(void* const* d_in, const int* in_sizes, int n_in,
                              void* d_out, int out_size, void* d_ws, size_t ws_size,
                              hipStream_t stream)
{
    const float* z1 = (const float*)d_in[0];
    const float* z2 = (const float*)d_in[1];
    float* out = (float*)d_out;

    char* ws = (char*)d_ws;
    unsigned char* Z8 = (unsigned char*)ws;              // 16384*256 = 4 MB
    float* pos  = (float*)(ws + 4194304);                // 32 KB
    float* S    = (float*)(ws + 4227072);                // 64 KB (fallback)
    float* part = (float*)(ws + 4292608);                // 8256*512*4 = 16.9 MB
    const size_t need = 4292608 + (size_t)NTRI * 512 * 4;

    // normalize zeroes S and out
    normalize_kernel<<<N_ROWS / 4, 256, 0, stream>>>(z1, z2, Z8, pos, S, out);

    if (ws_size >= need) {
        gram_kernel<true><<<NTRI, 256, 0, stream>>>(Z8, part, nullptr);
        reduce_loss_kernel<<<64, 1024, 0, stream>>>(part, pos, out);
    } else {
        gram_kernel<false><<<NTRI, 256, 0, stream>>>(Z8, nullptr, S);
        loss_kernel<<<N_ROWS / 256, 256, 0, stream>>>(S, pos, out);
    }
}